// Round 5
// baseline (675.151 us; speedup 1.0000x reference)
//
#include <hip/hip_runtime.h>

// LTC cell fused kernel. B=512, S=256, N=256, 6 unfolds.
// R5 vs R4:
//  - fp16 packed params: plane H = half2{a, a*mu} (4B/elem, dwordx4/quad),
//    plane W = half{w*erev} (2B/elem, dwordx2/quad). 12B -> 6B per element:
//    halves the per-pass L2 param stream (1.34GB -> 0.67GB total).
//  - distance-2 rolling register prefetch, fully-unrolled pass body (static
//    buffer indices), PLUS cross-pass prologue: last 2 iterations of each
//    pass prefetch the NEXT pass's first 2 quads (params are v-independent,
//    so the load stream never stalls on the per-step barriers).
//  - math unchanged: f2 pk ops, raw v_exp_f32/v_rcp_f32 (2 trans/sigmoid).

#define LOG2E 1.4426950408889634f
#define EXP2_RAW(x) __builtin_amdgcn_exp2f(x)
#define RCP_RAW(x) __builtin_amdgcn_rcpf(x)

typedef float f2 __attribute__((ext_vector_type(2)));
typedef _Float16 h2 __attribute__((ext_vector_type(2)));

constexpr int Bb = 512;
constexpr int Ss = 256;
constexpr int Nn = 256;
constexpr int UNFOLDS = 6;
constexpr float EPS = 1e-8f;
constexpr int QPASS = 16;     // quads per chunk per pass (64 i / 4)
constexpr int PLANE = 16384;  // (Nn/4)*Nn quad entries

struct alignas(16) HQ { h2 a[4]; };        // per i in quad: {a, a*mu}
struct alignas(8)  WQ { _Float16 w[4]; };  // per i in quad: w*erev

__global__ __launch_bounds__(256) void pack_kernel(
    const float* __restrict__ sg, const float* __restrict__ mu,
    const float* __restrict__ w, const float* __restrict__ er,
    const float* __restrict__ ssg, const float* __restrict__ smu,
    const float* __restrict__ sw, const float* __restrict__ ser,
    HQ* __restrict__ pH, WQ* __restrict__ pW,
    HQ* __restrict__ sH, WQ* __restrict__ sW) {
  int idx = blockIdx.x * 256 + threadIdx.x;   // iq*256 + j
  int b = (idx >> 8) * 1024 + (idx & 255);    // row 4*iq, col j
  HQ hq; WQ wq;
#pragma unroll
  for (int k = 0; k < 4; ++k) {
    int o = b + k * 256;
    float a = sg[o] * LOG2E;
    hq.a[k] = h2{(_Float16)a, (_Float16)(a * mu[o])};
    wq.w[k] = (_Float16)(w[o] * er[o]);
  }
  pH[idx] = hq; pW[idx] = wq;
#pragma unroll
  for (int k = 0; k < 4; ++k) {
    int o = b + k * 256;
    float a = ssg[o] * LOG2E;
    hq.a[k] = h2{(_Float16)a, (_Float16)(a * smu[o])};
    wq.w[k] = (_Float16)(sw[o] * ser[o]);
  }
  sH[idx] = hq; sW[idx] = wq;
}

struct Acc8 {
  f2 na0, nb0, da0, db0, na1, nb1, da1, db1;
};

// One contraction pass (64 i for chunk c, 2 rows). hbuf/wbuf[0..1] must hold
// cur-table quads 0,1 on entry; on exit they hold nxt-table quads 0,1.
__device__ __forceinline__ Acc8 pass_accum(
    const HQ* __restrict__ curH, const WQ* __restrict__ curW,
    const HQ* __restrict__ nxtH, const WQ* __restrict__ nxtW,
    const float* __restrict__ x0p, const float* __restrict__ x1p,
    int c, int j, HQ hbuf[2], WQ wbuf[2]) {
  Acc8 acc;
  acc.na0 = 0.f; acc.nb0 = 0.f; acc.da0 = 0.f; acc.db0 = 0.f;
  acc.na1 = 0.f; acc.nb1 = 0.f; acc.da1 = 0.f; acc.db1 = 0.f;
  const int qb = c * 4096 + j;
#pragma unroll
  for (int ip = 0; ip < QPASS; ++ip) {
    HQ hn; WQ wn;
    if (ip < QPASS - 2) {  // compile-time branch (full unroll)
      hn = curH[qb + (ip + 2) * 256];
      wn = curW[qb + (ip + 2) * 256];
    } else {
      hn = nxtH[qb + (ip - (QPASS - 2)) * 256];
      wn = nxtW[qb + (ip - (QPASS - 2)) * 256];
    }
    const HQ H = hbuf[ip & 1];   // static index under full unroll
    const WQ W = wbuf[ip & 1];
    const int ib = c * 64 + ip * 4;
    const float4 xq0 = *reinterpret_cast<const float4*>(&x0p[ib]);
    const float4 xq1 = *reinterpret_cast<const float4*>(&x1p[ib]);

    const f2 a01 = {(float)H.a[0].x, (float)H.a[1].x};
    const f2 a23 = {(float)H.a[2].x, (float)H.a[3].x};
    const f2 m01 = {(float)H.a[0].y, (float)H.a[1].y};
    const f2 m23 = {(float)H.a[2].y, (float)H.a[3].y};
    const f2 wn01 = {(float)W.w[0], (float)W.w[1]};
    const f2 wn23 = {(float)W.w[2], (float)W.w[3]};
    const f2 wd01 = {__builtin_fabsf(wn01.x), __builtin_fabsf(wn01.y)};
    const f2 wd23 = {__builtin_fabsf(wn23.x), __builtin_fabsf(wn23.y)};

    {  // row 0
      const f2 x01 = {xq0.x, xq0.y}, x23 = {xq0.z, xq0.w};
      const f2 y01 = m01 - a01 * x01;
      const f2 y23 = m23 - a23 * x23;
      f2 s01, s23;
      s01.x = RCP_RAW(1.f + EXP2_RAW(y01.x));
      s01.y = RCP_RAW(1.f + EXP2_RAW(y01.y));
      s23.x = RCP_RAW(1.f + EXP2_RAW(y23.x));
      s23.y = RCP_RAW(1.f + EXP2_RAW(y23.y));
      acc.na0 += wn01 * s01; acc.nb0 += wn23 * s23;
      acc.da0 += wd01 * s01; acc.db0 += wd23 * s23;
    }
    {  // row 1
      const f2 x01 = {xq1.x, xq1.y}, x23 = {xq1.z, xq1.w};
      const f2 y01 = m01 - a01 * x01;
      const f2 y23 = m23 - a23 * x23;
      f2 s01, s23;
      s01.x = RCP_RAW(1.f + EXP2_RAW(y01.x));
      s01.y = RCP_RAW(1.f + EXP2_RAW(y01.y));
      s23.x = RCP_RAW(1.f + EXP2_RAW(y23.x));
      s23.y = RCP_RAW(1.f + EXP2_RAW(y23.y));
      acc.na1 += wn01 * s01; acc.nb1 += wn23 * s23;
      acc.da1 += wd01 * s01; acc.db1 += wd23 * s23;
    }
    hbuf[ip & 1] = hn;
    wbuf[ip & 1] = wn;
  }
  return acc;
}

__global__ __launch_bounds__(1024, 1) void ltc_kernel(
    const float* __restrict__ input, const float* __restrict__ hx,
    const float* __restrict__ ts, const float* __restrict__ gleak,
    const float* __restrict__ vleak, const float* __restrict__ cm,
    const float* __restrict__ input_w, const float* __restrict__ input_b,
    const HQ* __restrict__ pH, const WQ* __restrict__ pW,
    const HQ* __restrict__ sH, const WQ* __restrict__ sW,
    float* __restrict__ out) {
  __shared__ alignas(16) float v_lds[2][Nn];
  __shared__ alignas(16) float inp_lds[2][Ss];
  __shared__ alignas(16) float4 red[1024];  // 16 KB

  const int tid = threadIdx.x;
  const int j = tid & 255;   // output column
  const int c = tid >> 8;    // i-chunk 0..3 (wave-uniform)
  const int b0 = blockIdx.x * 2;
  const int qb = c * 4096 + j;

  // Prologue prefetch (independent of LDS staging): sensory quads 0,1.
  HQ hbuf[2]; WQ wbuf[2];
  hbuf[0] = sH[qb];       wbuf[0] = sW[qb];
  hbuf[1] = sH[qb + 256]; wbuf[1] = sW[qb + 256];

  if (tid < 512) {
    int r = tid >> 8, s = tid & 255;
    inp_lds[r][s] = input[(b0 + r) * Ss + s] * input_w[s] + input_b[s];
    v_lds[r][s] = hx[(b0 + r) * Nn + s];
  }
  __syncthreads();

  // ---- sensory pass (prefetches pH/pW quads 0,1 at its tail) ----
  {
    Acc8 acc = pass_accum(sH, sW, pH, pW, &inp_lds[0][0], &inp_lds[1][0],
                          c, j, hbuf, wbuf);
    red[tid] = make_float4(acc.na0.x + acc.na0.y + acc.nb0.x + acc.nb0.y,
                           acc.da0.x + acc.da0.y + acc.db0.x + acc.db0.y,
                           acc.na1.x + acc.na1.y + acc.nb1.x + acc.nb1.y,
                           acc.da1.x + acc.da1.y + acc.db1.x + acc.db1.y);
  }
  __syncthreads();

  float snum0 = 0.f, sden0 = 0.f, snum1 = 0.f, sden1 = 0.f;
  float cmt0 = 0.f, cmt1 = 0.f, glj = 0.f, glvl = 0.f;
  if (c == 0) {
    float4 a = red[j], b = red[256 + j], cc = red[512 + j], d = red[768 + j];
    snum0 = a.x + b.x + cc.x + d.x;
    sden0 = a.y + b.y + cc.y + d.y;
    snum1 = a.z + b.z + cc.z + d.z;
    sden1 = a.w + b.w + cc.w + d.w;
    glj = gleak[j];
    glvl = glj * vleak[j];
    float cmj = cm[j];
    cmt0 = cmj / ((ts[b0] + 1.f) / (float)UNFOLDS);
    cmt1 = cmj / ((ts[b0 + 1] + 1.f) / (float)UNFOLDS);
  }
  __syncthreads();  // red[] reused by step loop

  // ---- 6 ODE unfolds, v resident in LDS ----
  float vo0 = 0.f, vo1 = 0.f;
  for (int step = 0; step < UNFOLDS; ++step) {
    Acc8 acc = pass_accum(pH, pW, pH, pW, &v_lds[0][0], &v_lds[1][0],
                          c, j, hbuf, wbuf);
    red[tid] = make_float4(acc.na0.x + acc.na0.y + acc.nb0.x + acc.nb0.y,
                           acc.da0.x + acc.da0.y + acc.db0.x + acc.db0.y,
                           acc.na1.x + acc.na1.y + acc.nb1.x + acc.nb1.y,
                           acc.da1.x + acc.da1.y + acc.db1.x + acc.db1.y);
    __syncthreads();
    if (c == 0) {
      float4 a = red[j], b = red[256 + j], cc = red[512 + j], d = red[768 + j];
      float num0 = a.x + b.x + cc.x + d.x + snum0;
      float den0 = a.y + b.y + cc.y + d.y + sden0;
      float num1 = a.z + b.z + cc.z + d.z + snum1;
      float den1 = a.w + b.w + cc.w + d.w + sden1;
      float v0 = v_lds[0][j], v1 = v_lds[1][j];
      vo0 = (cmt0 * v0 + glvl + num0) / (cmt0 + glj + den0 + EPS);
      vo1 = (cmt1 * v1 + glvl + num1) / (cmt1 + glj + den1 + EPS);
      v_lds[0][j] = vo0;
      v_lds[1][j] = vo1;
    }
    __syncthreads();
  }

  if (c == 0) {
    out[b0 * Nn + j] = vo0;
    out[(b0 + 1) * Nn + j] = vo1;
  }
}

// Correctness-only fallback (runs if ws too small): f32 on-the-fly params.
__global__ __launch_bounds__(1024, 1) void ltc_kernel_f32(
    const float* __restrict__ input, const float* __restrict__ hx,
    const float* __restrict__ ts, const float* __restrict__ gleak,
    const float* __restrict__ vleak, const float* __restrict__ cm,
    const float* __restrict__ input_w, const float* __restrict__ input_b,
    const float* __restrict__ sigmaP, const float* __restrict__ muP,
    const float* __restrict__ wP, const float* __restrict__ erevP,
    const float* __restrict__ ssigmaP, const float* __restrict__ smuP,
    const float* __restrict__ swP, const float* __restrict__ serevP,
    float* __restrict__ out) {
  __shared__ float v_lds[2][Nn];
  __shared__ float inp_lds[2][Ss];
  __shared__ float4 red[1024];
  const int tid = threadIdx.x, j = tid & 255, c = tid >> 8;
  const int b0 = blockIdx.x * 2;
  if (tid < 512) {
    int r = tid >> 8, s = tid & 255;
    inp_lds[r][s] = input[(b0 + r) * Ss + s] * input_w[s] + input_b[s];
    v_lds[r][s] = hx[(b0 + r) * Nn + s];
  }
  __syncthreads();
  float sn0 = 0.f, sd0 = 0.f, sn1 = 0.f, sd1 = 0.f;
  for (int i = c * 64; i < c * 64 + 64; ++i) {
    int idx = i * Nn + j;
    float a = ssigmaP[idx] * LOG2E, m = a * smuP[idx],
          ws = swP[idx] * serevP[idx];
    float s0 = RCP_RAW(1.f + EXP2_RAW(m - a * inp_lds[0][i]));
    float s1 = RCP_RAW(1.f + EXP2_RAW(m - a * inp_lds[1][i]));
    sn0 += ws * s0; sd0 += __builtin_fabsf(ws) * s0;
    sn1 += ws * s1; sd1 += __builtin_fabsf(ws) * s1;
  }
  red[tid] = make_float4(sn0, sd0, sn1, sd1);
  __syncthreads();
  float snum0 = 0, sden0 = 0, snum1 = 0, sden1 = 0, cmt0 = 0, cmt1 = 0,
        glj = 0, glvl = 0;
  if (c == 0) {
    float4 a = red[j], b = red[256 + j], cc = red[512 + j], d = red[768 + j];
    snum0 = a.x + b.x + cc.x + d.x; sden0 = a.y + b.y + cc.y + d.y;
    snum1 = a.z + b.z + cc.z + d.z; sden1 = a.w + b.w + cc.w + d.w;
    glj = gleak[j]; glvl = glj * vleak[j];
    cmt0 = cm[j] / ((ts[b0] + 1.f) / (float)UNFOLDS);
    cmt1 = cm[j] / ((ts[b0 + 1] + 1.f) / (float)UNFOLDS);
  }
  __syncthreads();
  float vo0 = 0.f, vo1 = 0.f;
  for (int step = 0; step < UNFOLDS; ++step) {
    float n0 = 0, d0 = 0, n1 = 0, d1 = 0;
    for (int i = c * 64; i < c * 64 + 64; ++i) {
      int idx = i * Nn + j;
      float a = sigmaP[idx] * LOG2E, m = a * muP[idx],
            ws = wP[idx] * erevP[idx];
      float s0 = RCP_RAW(1.f + EXP2_RAW(m - a * v_lds[0][i]));
      float s1 = RCP_RAW(1.f + EXP2_RAW(m - a * v_lds[1][i]));
      n0 += ws * s0; d0 += __builtin_fabsf(ws) * s0;
      n1 += ws * s1; d1 += __builtin_fabsf(ws) * s1;
    }
    red[tid] = make_float4(n0, d0, n1, d1);
    __syncthreads();
    if (c == 0) {
      float4 a = red[j], b = red[256 + j], cc = red[512 + j], d = red[768 + j];
      float num0 = a.x + b.x + cc.x + d.x + snum0;
      float den0 = a.y + b.y + cc.y + d.y + sden0;
      float num1 = a.z + b.z + cc.z + d.z + snum1;
      float den1 = a.w + b.w + cc.w + d.w + sden1;
      vo0 = (cmt0 * v_lds[0][j] + glvl + num0) / (cmt0 + glj + den0 + EPS);
      vo1 = (cmt1 * v_lds[1][j] + glvl + num1) / (cmt1 + glj + den1 + EPS);
      v_lds[0][j] = vo0; v_lds[1][j] = vo1;
    }
    __syncthreads();
  }
  if (c == 0) {
    out[b0 * Nn + j] = vo0;
    out[(b0 + 1) * Nn + j] = vo1;
  }
}

extern "C" void kernel_launch(void* const* d_in, const int* in_sizes, int n_in,
                              void* d_out, int out_size, void* d_ws, size_t ws_size,
                              hipStream_t stream) {
  const float* input   = (const float*)d_in[0];
  const float* hx      = (const float*)d_in[1];
  const float* ts      = (const float*)d_in[2];
  const float* gleak   = (const float*)d_in[3];
  const float* vleak   = (const float*)d_in[4];
  const float* cm      = (const float*)d_in[5];
  const float* sigma   = (const float*)d_in[6];
  const float* mu      = (const float*)d_in[7];
  const float* w       = (const float*)d_in[8];
  const float* erev    = (const float*)d_in[9];
  const float* ssigma  = (const float*)d_in[10];
  const float* smu     = (const float*)d_in[11];
  const float* sw      = (const float*)d_in[12];
  const float* serev   = (const float*)d_in[13];
  const float* input_w = (const float*)d_in[14];
  const float* input_b = (const float*)d_in[15];
  float* out = (float*)d_out;

  // pH 256KB | sH 256KB | pW 128KB | sW 128KB = 768KB
  const size_t need = (size_t)PLANE * (sizeof(HQ) * 2 + sizeof(WQ) * 2);
  if (ws_size >= need) {
    HQ* pH = (HQ*)d_ws;
    HQ* sH = pH + PLANE;
    WQ* pW = (WQ*)(sH + PLANE);
    WQ* sW = pW + PLANE;
    pack_kernel<<<PLANE / 256, 256, 0, stream>>>(sigma, mu, w, erev, ssigma,
                                                 smu, sw, serev, pH, pW, sH, sW);
    ltc_kernel<<<Bb / 2, 1024, 0, stream>>>(
        input, hx, ts, gleak, vleak, cm, input_w, input_b, pH, pW, sH, sW, out);
  } else {
    ltc_kernel_f32<<<Bb / 2, 1024, 0, stream>>>(
        input, hx, ts, gleak, vleak, cm, input_w, input_b,
        sigma, mu, w, erev, ssigma, smu, sw, serev, out);
  }
}

// Round 7
// 266.794 us; speedup vs baseline: 2.5306x; 2.5306x over previous
//
#include <hip/hip_runtime.h>

// LTC cell fused kernel. B=512, S=256, N=256, 6 unfolds.
// R6 = R5's design with the scratch-spill bug fixed (resubmitted after broker
// timeout):
//  - R5 passed the rolling prefetch buffers as HQ[2] array->pointer function
//    args; compiler kept them in SCRATCH (rule #20): 1.4GB of HBM scratch
//    traffic, 607us. R6 keeps the double-buffer in NAMED locals (hA,hB,wA,wB)
//    and fully macro-expands the 16-iteration pass body - every access is
//    lexically a named register, nothing can hit scratch.
//  - fp16 packed params: HQ plane = half2{a, a*mu} (16B/quad, dwordx4),
//    WQ plane = half{w*erev} (8B/quad, dwordx2). 6B/elem total.
//  - distance-2 rolling prefetch + cross-pass prologue: iterations 14,15 of
//    each pass prefetch the NEXT pass's quads 0,1 (params are v-independent,
//    so the load stream never stalls across the per-step barriers).

#define LOG2E 1.4426950408889634f
#define EXP2_RAW(x) __builtin_amdgcn_exp2f(x)
#define RCP_RAW(x) __builtin_amdgcn_rcpf(x)

typedef float f2 __attribute__((ext_vector_type(2)));
typedef _Float16 h2 __attribute__((ext_vector_type(2)));

constexpr int Bb = 512;
constexpr int Ss = 256;
constexpr int Nn = 256;
constexpr int UNFOLDS = 6;
constexpr float EPS = 1e-8f;
constexpr int PLANE = 16384;  // (Nn/4)*Nn quad entries

struct alignas(16) HQ { h2 a[4]; };        // per i in quad: {a, a*mu}
struct alignas(8)  WQ { _Float16 w[4]; };  // per i in quad: w*erev

__global__ __launch_bounds__(256) void pack_kernel(
    const float* __restrict__ sg, const float* __restrict__ mu,
    const float* __restrict__ w, const float* __restrict__ er,
    const float* __restrict__ ssg, const float* __restrict__ smu,
    const float* __restrict__ sw, const float* __restrict__ ser,
    HQ* __restrict__ pH, WQ* __restrict__ pW,
    HQ* __restrict__ sH, WQ* __restrict__ sW) {
  int idx = blockIdx.x * 256 + threadIdx.x;   // iq*256 + j
  int b = (idx >> 8) * 1024 + (idx & 255);    // row 4*iq, col j
  HQ hq; WQ wq;
#pragma unroll
  for (int k = 0; k < 4; ++k) {
    int o = b + k * 256;
    float a = sg[o] * LOG2E;
    hq.a[k] = h2{(_Float16)a, (_Float16)(a * mu[o])};
    wq.w[k] = (_Float16)(w[o] * er[o]);
  }
  pH[idx] = hq; pW[idx] = wq;
#pragma unroll
  for (int k = 0; k < 4; ++k) {
    int o = b + k * 256;
    float a = ssg[o] * LOG2E;
    hq.a[k] = h2{(_Float16)a, (_Float16)(a * smu[o])};
    wq.w[k] = (_Float16)(sw[o] * ser[o]);
  }
  sH[idx] = hq; sW[idx] = wq;
}

// One ip-iteration: consume HREG/WREG (params for quad IPIDX), accumulate 8
// sigmoids (4 i x 2 rows), then overwrite HREG/WREG with prefetched quad NIDX
// from table NH/NW. All names resolve to kernel-scope named locals.
#define IP_STEP(HREG, WREG, NH, NW, NIDX, IPIDX)                             \
  {                                                                          \
    const HQ hn_ = (NH)[qb + (NIDX) * 256];                                  \
    const WQ wn_ = (NW)[qb + (NIDX) * 256];                                  \
    const int ib_ = c * 64 + (IPIDX) * 4;                                    \
    const float4 xq0_ = *reinterpret_cast<const float4*>(&xp0_[ib_]);        \
    const float4 xq1_ = *reinterpret_cast<const float4*>(&xp1_[ib_]);        \
    const f2 a01_ = {(float)HREG.a[0].x, (float)HREG.a[1].x};                \
    const f2 a23_ = {(float)HREG.a[2].x, (float)HREG.a[3].x};                \
    const f2 m01_ = {(float)HREG.a[0].y, (float)HREG.a[1].y};                \
    const f2 m23_ = {(float)HREG.a[2].y, (float)HREG.a[3].y};                \
    const f2 wn01_ = {(float)WREG.w[0], (float)WREG.w[1]};                   \
    const f2 wn23_ = {(float)WREG.w[2], (float)WREG.w[3]};                   \
    const f2 wd01_ = {__builtin_fabsf(wn01_.x), __builtin_fabsf(wn01_.y)};   \
    const f2 wd23_ = {__builtin_fabsf(wn23_.x), __builtin_fabsf(wn23_.y)};   \
    {                                                                        \
      const f2 x01_ = {xq0_.x, xq0_.y}, x23_ = {xq0_.z, xq0_.w};             \
      const f2 y01_ = m01_ - a01_ * x01_;                                    \
      const f2 y23_ = m23_ - a23_ * x23_;                                    \
      f2 t01_, t23_, s01_, s23_;                                             \
      t01_.x = EXP2_RAW(y01_.x); t01_.y = EXP2_RAW(y01_.y);                  \
      t23_.x = EXP2_RAW(y23_.x); t23_.y = EXP2_RAW(y23_.y);                  \
      const f2 u01_ = t01_ + 1.0f, u23_ = t23_ + 1.0f;                       \
      s01_.x = RCP_RAW(u01_.x); s01_.y = RCP_RAW(u01_.y);                    \
      s23_.x = RCP_RAW(u23_.x); s23_.y = RCP_RAW(u23_.y);                    \
      na0 += wn01_ * s01_; nb0 += wn23_ * s23_;                              \
      da0 += wd01_ * s01_; db0 += wd23_ * s23_;                              \
    }                                                                        \
    {                                                                        \
      const f2 x01_ = {xq1_.x, xq1_.y}, x23_ = {xq1_.z, xq1_.w};             \
      const f2 y01_ = m01_ - a01_ * x01_;                                    \
      const f2 y23_ = m23_ - a23_ * x23_;                                    \
      f2 t01_, t23_, s01_, s23_;                                             \
      t01_.x = EXP2_RAW(y01_.x); t01_.y = EXP2_RAW(y01_.y);                  \
      t23_.x = EXP2_RAW(y23_.x); t23_.y = EXP2_RAW(y23_.y);                  \
      const f2 u01_ = t01_ + 1.0f, u23_ = t23_ + 1.0f;                       \
      s01_.x = RCP_RAW(u01_.x); s01_.y = RCP_RAW(u01_.y);                    \
      s23_.x = RCP_RAW(u23_.x); s23_.y = RCP_RAW(u23_.y);                    \
      na1 += wn01_ * s01_; nb1 += wn23_ * s23_;                              \
      da1 += wd01_ * s01_; db1 += wd23_ * s23_;                              \
    }                                                                        \
    HREG = hn_; WREG = wn_;                                                  \
  }

// One full contraction pass (16 quads). On entry hA/hB hold quads 0,1 of CH;
// on exit they hold quads 0,1 of NH (cross-pass prefetch at ip=14,15).
#define LTC_PASS(CH, CW, NH, NW, XP0, XP1)                                   \
  {                                                                          \
    const float* xp0_ = (XP0);                                               \
    const float* xp1_ = (XP1);                                               \
    na0 = 0.f; nb0 = 0.f; da0 = 0.f; db0 = 0.f;                              \
    na1 = 0.f; nb1 = 0.f; da1 = 0.f; db1 = 0.f;                              \
    IP_STEP(hA, wA, CH, CW, 2, 0)                                            \
    IP_STEP(hB, wB, CH, CW, 3, 1)                                            \
    IP_STEP(hA, wA, CH, CW, 4, 2)                                            \
    IP_STEP(hB, wB, CH, CW, 5, 3)                                            \
    IP_STEP(hA, wA, CH, CW, 6, 4)                                            \
    IP_STEP(hB, wB, CH, CW, 7, 5)                                            \
    IP_STEP(hA, wA, CH, CW, 8, 6)                                            \
    IP_STEP(hB, wB, CH, CW, 9, 7)                                            \
    IP_STEP(hA, wA, CH, CW, 10, 8)                                           \
    IP_STEP(hB, wB, CH, CW, 11, 9)                                           \
    IP_STEP(hA, wA, CH, CW, 12, 10)                                          \
    IP_STEP(hB, wB, CH, CW, 13, 11)                                          \
    IP_STEP(hA, wA, CH, CW, 14, 12)                                          \
    IP_STEP(hB, wB, CH, CW, 15, 13)                                          \
    IP_STEP(hA, wA, NH, NW, 0, 14)                                           \
    IP_STEP(hB, wB, NH, NW, 1, 15)                                           \
  }

__global__ __launch_bounds__(1024, 1) void ltc_kernel(
    const float* __restrict__ input, const float* __restrict__ hx,
    const float* __restrict__ ts, const float* __restrict__ gleak,
    const float* __restrict__ vleak, const float* __restrict__ cm,
    const float* __restrict__ input_w, const float* __restrict__ input_b,
    const HQ* __restrict__ pH, const WQ* __restrict__ pW,
    const HQ* __restrict__ sH, const WQ* __restrict__ sW,
    float* __restrict__ out) {
  __shared__ alignas(16) float v_lds[2][Nn];
  __shared__ alignas(16) float inp_lds[2][Ss];
  __shared__ alignas(16) float4 red[1024];  // 16 KB

  const int tid = threadIdx.x;
  const int j = tid & 255;   // output column
  const int c = tid >> 8;    // i-chunk 0..3 (wave-uniform)
  const int b0 = blockIdx.x * 2;
  const int qb = c * 4096 + j;

  // Rolling double-buffer: NAMED locals only (no arrays -> no scratch).
  HQ hA, hB; WQ wA, wB;
  f2 na0, nb0, da0, db0, na1, nb1, da1, db1;

  // Prologue prefetch (independent of LDS staging): sensory quads 0,1.
  hA = sH[qb];       wA = sW[qb];
  hB = sH[qb + 256]; wB = sW[qb + 256];

  if (tid < 512) {
    int r = tid >> 8, s = tid & 255;
    inp_lds[r][s] = input[(b0 + r) * Ss + s] * input_w[s] + input_b[s];
    v_lds[r][s] = hx[(b0 + r) * Nn + s];
  }
  __syncthreads();

  // ---- sensory pass (tail prefetches pH/pW quads 0,1) ----
  LTC_PASS(sH, sW, pH, pW, &inp_lds[0][0], &inp_lds[1][0]);
  red[tid] = make_float4(na0.x + na0.y + nb0.x + nb0.y,
                         da0.x + da0.y + db0.x + db0.y,
                         na1.x + na1.y + nb1.x + nb1.y,
                         da1.x + da1.y + db1.x + db1.y);
  __syncthreads();

  float snum0 = 0.f, sden0 = 0.f, snum1 = 0.f, sden1 = 0.f;
  float cmt0 = 0.f, cmt1 = 0.f, glj = 0.f, glvl = 0.f;
  if (c == 0) {
    float4 a = red[j], b = red[256 + j], cc = red[512 + j], d = red[768 + j];
    snum0 = a.x + b.x + cc.x + d.x;
    sden0 = a.y + b.y + cc.y + d.y;
    snum1 = a.z + b.z + cc.z + d.z;
    sden1 = a.w + b.w + cc.w + d.w;
    glj = gleak[j];
    glvl = glj * vleak[j];
    float cmj = cm[j];
    cmt0 = cmj / ((ts[b0] + 1.f) / (float)UNFOLDS);
    cmt1 = cmj / ((ts[b0 + 1] + 1.f) / (float)UNFOLDS);
  }
  __syncthreads();  // red[] reused by step loop

  // ---- 6 ODE unfolds, v resident in LDS ----
  float vo0 = 0.f, vo1 = 0.f;
  for (int step = 0; step < UNFOLDS; ++step) {
    LTC_PASS(pH, pW, pH, pW, &v_lds[0][0], &v_lds[1][0]);
    red[tid] = make_float4(na0.x + na0.y + nb0.x + nb0.y,
                           da0.x + da0.y + db0.x + db0.y,
                           na1.x + na1.y + nb1.x + nb1.y,
                           da1.x + da1.y + db1.x + db1.y);
    __syncthreads();
    if (c == 0) {
      float4 a = red[j], b = red[256 + j], cc = red[512 + j], d = red[768 + j];
      float num0 = a.x + b.x + cc.x + d.x + snum0;
      float den0 = a.y + b.y + cc.y + d.y + sden0;
      float num1 = a.z + b.z + cc.z + d.z + snum1;
      float den1 = a.w + b.w + cc.w + d.w + sden1;
      float v0 = v_lds[0][j], v1 = v_lds[1][j];
      vo0 = (cmt0 * v0 + glvl + num0) / (cmt0 + glj + den0 + EPS);
      vo1 = (cmt1 * v1 + glvl + num1) / (cmt1 + glj + den1 + EPS);
      v_lds[0][j] = vo0;
      v_lds[1][j] = vo1;
    }
    __syncthreads();
  }

  if (c == 0) {
    out[b0 * Nn + j] = vo0;
    out[(b0 + 1) * Nn + j] = vo1;
  }
}

// Correctness-only fallback (runs if ws too small): f32 on-the-fly params.
__global__ __launch_bounds__(1024, 1) void ltc_kernel_f32(
    const float* __restrict__ input, const float* __restrict__ hx,
    const float* __restrict__ ts, const float* __restrict__ gleak,
    const float* __restrict__ vleak, const float* __restrict__ cm,
    const float* __restrict__ input_w, const float* __restrict__ input_b,
    const float* __restrict__ sigmaP, const float* __restrict__ muP,
    const float* __restrict__ wP, const float* __restrict__ erevP,
    const float* __restrict__ ssigmaP, const float* __restrict__ smuP,
    const float* __restrict__ swP, const float* __restrict__ serevP,
    float* __restrict__ out) {
  __shared__ float v_lds[2][Nn];
  __shared__ float inp_lds[2][Ss];
  __shared__ float4 red[1024];
  const int tid = threadIdx.x, j = tid & 255, c = tid >> 8;
  const int b0 = blockIdx.x * 2;
  if (tid < 512) {
    int r = tid >> 8, s = tid & 255;
    inp_lds[r][s] = input[(b0 + r) * Ss + s] * input_w[s] + input_b[s];
    v_lds[r][s] = hx[(b0 + r) * Nn + s];
  }
  __syncthreads();
  float sn0 = 0.f, sd0 = 0.f, sn1 = 0.f, sd1 = 0.f;
  for (int i = c * 64; i < c * 64 + 64; ++i) {
    int idx = i * Nn + j;
    float a = ssigmaP[idx] * LOG2E, m = a * smuP[idx],
          ws = swP[idx] * serevP[idx];
    float s0 = RCP_RAW(1.f + EXP2_RAW(m - a * inp_lds[0][i]));
    float s1 = RCP_RAW(1.f + EXP2_RAW(m - a * inp_lds[1][i]));
    sn0 += ws * s0; sd0 += __builtin_fabsf(ws) * s0;
    sn1 += ws * s1; sd1 += __builtin_fabsf(ws) * s1;
  }
  red[tid] = make_float4(sn0, sd0, sn1, sd1);
  __syncthreads();
  float snum0 = 0, sden0 = 0, snum1 = 0, sden1 = 0, cmt0 = 0, cmt1 = 0,
        glj = 0, glvl = 0;
  if (c == 0) {
    float4 a = red[j], b = red[256 + j], cc = red[512 + j], d = red[768 + j];
    snum0 = a.x + b.x + cc.x + d.x; sden0 = a.y + b.y + cc.y + d.y;
    snum1 = a.z + b.z + cc.z + d.z; sden1 = a.w + b.w + cc.w + d.w;
    glj = gleak[j]; glvl = glj * vleak[j];
    cmt0 = cm[j] / ((ts[b0] + 1.f) / (float)UNFOLDS);
    cmt1 = cm[j] / ((ts[b0 + 1] + 1.f) / (float)UNFOLDS);
  }
  __syncthreads();
  float vo0 = 0.f, vo1 = 0.f;
  for (int step = 0; step < UNFOLDS; ++step) {
    float n0 = 0, d0 = 0, n1 = 0, d1 = 0;
    for (int i = c * 64; i < c * 64 + 64; ++i) {
      int idx = i * Nn + j;
      float a = sigmaP[idx] * LOG2E, m = a * muP[idx],
            ws = wP[idx] * erevP[idx];
      float s0 = RCP_RAW(1.f + EXP2_RAW(m - a * v_lds[0][i]));
      float s1 = RCP_RAW(1.f + EXP2_RAW(m - a * v_lds[1][i]));
      n0 += ws * s0; d0 += __builtin_fabsf(ws) * s0;
      n1 += ws * s1; d1 += __builtin_fabsf(ws) * s1;
    }
    red[tid] = make_float4(n0, d0, n1, d1);
    __syncthreads();
    if (c == 0) {
      float4 a = red[j], b = red[256 + j], cc = red[512 + j], d = red[768 + j];
      float num0 = a.x + b.x + cc.x + d.x + snum0;
      float den0 = a.y + b.y + cc.y + d.y + sden0;
      float num1 = a.z + b.z + cc.z + d.z + snum1;
      float den1 = a.w + b.w + cc.w + d.w + sden1;
      vo0 = (cmt0 * v_lds[0][j] + glvl + num0) / (cmt0 + glj + den0 + EPS);
      vo1 = (cmt1 * v_lds[1][j] + glvl + num1) / (cmt1 + glj + den1 + EPS);
      v_lds[0][j] = vo0; v_lds[1][j] = vo1;
    }
    __syncthreads();
  }
  if (c == 0) {
    out[b0 * Nn + j] = vo0;
    out[(b0 + 1) * Nn + j] = vo1;
  }
}

extern "C" void kernel_launch(void* const* d_in, const int* in_sizes, int n_in,
                              void* d_out, int out_size, void* d_ws, size_t ws_size,
                              hipStream_t stream) {
  const float* input   = (const float*)d_in[0];
  const float* hx      = (const float*)d_in[1];
  const float* ts      = (const float*)d_in[2];
  const float* gleak   = (const float*)d_in[3];
  const float* vleak   = (const float*)d_in[4];
  const float* cm      = (const float*)d_in[5];
  const float* sigma   = (const float*)d_in[6];
  const float* mu      = (const float*)d_in[7];
  const float* w       = (const float*)d_in[8];
  const float* erev    = (const float*)d_in[9];
  const float* ssigma  = (const float*)d_in[10];
  const float* smu     = (const float*)d_in[11];
  const float* sw      = (const float*)d_in[12];
  const float* serev   = (const float*)d_in[13];
  const float* input_w = (const float*)d_in[14];
  const float* input_b = (const float*)d_in[15];
  float* out = (float*)d_out;

  // pH 256KB | sH 256KB | pW 128KB | sW 128KB = 768KB
  const size_t need = (size_t)PLANE * (sizeof(HQ) * 2 + sizeof(WQ) * 2);
  if (ws_size >= need) {
    HQ* pH = (HQ*)d_ws;
    HQ* sH = pH + PLANE;
    WQ* pW = (WQ*)(sH + PLANE);
    WQ* sW = pW + PLANE;
    pack_kernel<<<PLANE / 256, 256, 0, stream>>>(sigma, mu, w, erev, ssigma,
                                                 smu, sw, serev, pH, pW, sH, sW);
    ltc_kernel<<<Bb / 2, 1024, 0, stream>>>(
        input, hx, ts, gleak, vleak, cm, input_w, input_b, pH, pW, sH, sW, out);
  } else {
    ltc_kernel_f32<<<Bb / 2, 1024, 0, stream>>>(
        input, hx, ts, gleak, vleak, cm, input_w, input_b,
        sigma, mu, w, erev, ssigma, smu, sw, serev, out);
  }
}

// Round 8
// 151.690 us; speedup vs baseline: 4.4509x; 1.7588x over previous
//
#include <hip/hip_runtime.h>

// LTC cell fused kernel. B=512, S=256, N=256, 6 unfolds.
// R8 = R4's proven structure (71.2us, VGPR=48, no spill) + fp16 tables ONLY.
//  - R5/R6 lesson: fully-unrolled straight-line pass bodies let the scheduler
//    hoist many iterations' loads -> live-range explosion -> scratch spill
//    (WRITE_SIZE 175-425MB). R4's loop + #pragma unroll 2 keeps the window
//    small: no spill. So: keep R4's loop shape exactly.
//  - fp16 packed params: HQ plane = half2{a=sigma*log2e, a*mu} (16B/quad,
//    dwordx4), WQ plane = half{w*erev} (8B/quad, dwordx2). 6B/elem vs R4's
//    12B: halves the per-pass L2 param stream (1.34GB -> 0.67GB) to pull
//    per-XCD L2 load out of the queuing knee (55% -> ~27%).
//  - math: raw v_exp_f32 / v_rcp_f32, f2 pk ops, |w| via fabs modifier.

#define LOG2E 1.4426950408889634f
#define EXP2_RAW(x) __builtin_amdgcn_exp2f(x)
#define RCP_RAW(x) __builtin_amdgcn_rcpf(x)

typedef float f2 __attribute__((ext_vector_type(2)));
typedef _Float16 h2 __attribute__((ext_vector_type(2)));

constexpr int Bb = 512;
constexpr int Ss = 256;
constexpr int Nn = 256;
constexpr int UNFOLDS = 6;
constexpr float EPS = 1e-8f;
constexpr int PLANE = 16384;  // (Nn/4)*Nn quad entries

struct alignas(16) HQ { h2 a[4]; };        // per i in quad: {a, a*mu}
struct alignas(8)  WQ { _Float16 w[4]; };  // per i in quad: w*erev

__global__ __launch_bounds__(256) void pack_kernel(
    const float* __restrict__ sg, const float* __restrict__ mu,
    const float* __restrict__ w, const float* __restrict__ er,
    const float* __restrict__ ssg, const float* __restrict__ smu,
    const float* __restrict__ sw, const float* __restrict__ ser,
    HQ* __restrict__ pH, WQ* __restrict__ pW,
    HQ* __restrict__ sH, WQ* __restrict__ sW) {
  int idx = blockIdx.x * 256 + threadIdx.x;   // iq*256 + j
  int b = (idx >> 8) * 1024 + (idx & 255);    // row 4*iq, col j
  HQ hq; WQ wq;
#pragma unroll
  for (int k = 0; k < 4; ++k) {
    int o = b + k * 256;
    float a = sg[o] * LOG2E;
    hq.a[k] = h2{(_Float16)a, (_Float16)(a * mu[o])};
    wq.w[k] = (_Float16)(w[o] * er[o]);
  }
  pH[idx] = hq; pW[idx] = wq;
#pragma unroll
  for (int k = 0; k < 4; ++k) {
    int o = b + k * 256;
    float a = ssg[o] * LOG2E;
    hq.a[k] = h2{(_Float16)a, (_Float16)(a * smu[o])};
    wq.w[k] = (_Float16)(sw[o] * ser[o]);
  }
  sH[idx] = hq; sW[idx] = wq;
}

struct Acc8 {
  f2 na0, nb0, da0, db0, na1, nb1, da1, db1;
};

// One full contraction pass (64 i-values for chunk c, 2 rows), R4 structure:
// loop over 16 quads, manual distance-1 rotation, #pragma unroll 2 (small
// scheduling window -> no spill).
template <bool PACKED>
__device__ __forceinline__ Acc8 pass_accum(
    const HQ* __restrict__ pH, const WQ* __restrict__ pW,
    const float* __restrict__ rS, const float* __restrict__ rM,
    const float* __restrict__ rW, const float* __restrict__ rE,
    const float* x0p, const float* x1p, int c, int j) {
  Acc8 acc;
  acc.na0 = 0.f; acc.nb0 = 0.f; acc.da0 = 0.f; acc.db0 = 0.f;
  acc.na1 = 0.f; acc.nb1 = 0.f; acc.da1 = 0.f; acc.db1 = 0.f;
  const int pb0 = c * 4096 + j;
  HQ H; WQ W;
  if constexpr (PACKED) { H = pH[pb0]; W = pW[pb0]; }
#pragma unroll 2
  for (int ip = 0; ip < 16; ++ip) {
    HQ Hn; WQ Wn;
    f2 a01, a23, m01, m23, wn01, wn23;
    if constexpr (PACKED) {
      // prefetch NEXT quad's params (wraps on last iter; harmless reload)
      const int ni = pb0 + (((ip + 1) & 15) << 8);
      Hn = pH[ni]; Wn = pW[ni];
      a01 = f2{(float)H.a[0].x, (float)H.a[1].x};
      a23 = f2{(float)H.a[2].x, (float)H.a[3].x};
      m01 = f2{(float)H.a[0].y, (float)H.a[1].y};
      m23 = f2{(float)H.a[2].y, (float)H.a[3].y};
      wn01 = f2{(float)W.w[0], (float)W.w[1]};
      wn23 = f2{(float)W.w[2], (float)W.w[3]};
    } else {
      const int b = (c * 64 + ip * 4) * Nn + j;
      a01 = f2{rS[b] * LOG2E, rS[b + 256] * LOG2E};
      a23 = f2{rS[b + 512] * LOG2E, rS[b + 768] * LOG2E};
      m01 = f2{a01.x * rM[b], a01.y * rM[b + 256]};
      m23 = f2{a23.x * rM[b + 512], a23.y * rM[b + 768]};
      wn01 = f2{rW[b] * rE[b], rW[b + 256] * rE[b + 256]};
      wn23 = f2{rW[b + 512] * rE[b + 512], rW[b + 768] * rE[b + 768]};
    }
    const f2 wd01 = {__builtin_fabsf(wn01.x), __builtin_fabsf(wn01.y)};
    const f2 wd23 = {__builtin_fabsf(wn23.x), __builtin_fabsf(wn23.y)};
    const int ib = c * 64 + ip * 4;
    const float4 xq0 = *reinterpret_cast<const float4*>(&x0p[ib]);
    const float4 xq1 = *reinterpret_cast<const float4*>(&x1p[ib]);

    {  // row 0
      const f2 x01 = {xq0.x, xq0.y}, x23 = {xq0.z, xq0.w};
      const f2 y01 = m01 - a01 * x01;
      const f2 y23 = m23 - a23 * x23;
      f2 s01, s23;
      s01.x = RCP_RAW(1.f + EXP2_RAW(y01.x));
      s01.y = RCP_RAW(1.f + EXP2_RAW(y01.y));
      s23.x = RCP_RAW(1.f + EXP2_RAW(y23.x));
      s23.y = RCP_RAW(1.f + EXP2_RAW(y23.y));
      acc.na0 += wn01 * s01; acc.nb0 += wn23 * s23;
      acc.da0 += wd01 * s01; acc.db0 += wd23 * s23;
    }
    {  // row 1
      const f2 x01 = {xq1.x, xq1.y}, x23 = {xq1.z, xq1.w};
      const f2 y01 = m01 - a01 * x01;
      const f2 y23 = m23 - a23 * x23;
      f2 s01, s23;
      s01.x = RCP_RAW(1.f + EXP2_RAW(y01.x));
      s01.y = RCP_RAW(1.f + EXP2_RAW(y01.y));
      s23.x = RCP_RAW(1.f + EXP2_RAW(y23.x));
      s23.y = RCP_RAW(1.f + EXP2_RAW(y23.y));
      acc.na1 += wn01 * s01; acc.nb1 += wn23 * s23;
      acc.da1 += wd01 * s01; acc.db1 += wd23 * s23;
    }
    if constexpr (PACKED) { H = Hn; W = Wn; }
  }
  return acc;
}

template <bool PACKED>
__global__ __launch_bounds__(1024, 1) void ltc_kernel(
    const float* __restrict__ input, const float* __restrict__ hx,
    const float* __restrict__ ts, const float* __restrict__ gleak,
    const float* __restrict__ vleak, const float* __restrict__ cm,
    const float* __restrict__ input_w, const float* __restrict__ input_b,
    const HQ* __restrict__ pH, const WQ* __restrict__ pW,
    const HQ* __restrict__ sH, const WQ* __restrict__ sW,
    const float* __restrict__ sigmaP, const float* __restrict__ muP,
    const float* __restrict__ wP, const float* __restrict__ erevP,
    const float* __restrict__ ssigmaP, const float* __restrict__ smuP,
    const float* __restrict__ swP, const float* __restrict__ serevP,
    float* __restrict__ out) {
  __shared__ alignas(16) float v_lds[2][Nn];
  __shared__ alignas(16) float inp_lds[2][Ss];
  __shared__ alignas(16) float4 red[1024];  // 16 KB

  const int tid = threadIdx.x;
  const int j = tid & 255;   // output column
  const int c = tid >> 8;    // i-chunk 0..3 (wave-uniform)
  const int b0 = blockIdx.x * 2;

  if (tid < 512) {
    int r = tid >> 8, s = tid & 255;
    inp_lds[r][s] = input[(b0 + r) * Ss + s] * input_w[s] + input_b[s];
    v_lds[r][s] = hx[(b0 + r) * Nn + s];
  }
  __syncthreads();

  // ---- sensory pass ----
  {
    Acc8 acc = pass_accum<PACKED>(sH, sW, ssigmaP, smuP, swP, serevP,
                                  &inp_lds[0][0], &inp_lds[1][0], c, j);
    red[tid] = make_float4(acc.na0.x + acc.na0.y + acc.nb0.x + acc.nb0.y,
                           acc.da0.x + acc.da0.y + acc.db0.x + acc.db0.y,
                           acc.na1.x + acc.na1.y + acc.nb1.x + acc.nb1.y,
                           acc.da1.x + acc.da1.y + acc.db1.x + acc.db1.y);
  }
  __syncthreads();

  float snum0 = 0.f, sden0 = 0.f, snum1 = 0.f, sden1 = 0.f;
  float cmt0 = 0.f, cmt1 = 0.f, glj = 0.f, glvl = 0.f;
  if (c == 0) {
    float4 a = red[j], b = red[256 + j], cc = red[512 + j], d = red[768 + j];
    snum0 = a.x + b.x + cc.x + d.x;
    sden0 = a.y + b.y + cc.y + d.y;
    snum1 = a.z + b.z + cc.z + d.z;
    sden1 = a.w + b.w + cc.w + d.w;
    glj = gleak[j];
    glvl = glj * vleak[j];
    float cmj = cm[j];
    cmt0 = cmj / ((ts[b0] + 1.f) / (float)UNFOLDS);
    cmt1 = cmj / ((ts[b0 + 1] + 1.f) / (float)UNFOLDS);
  }
  __syncthreads();  // red[] reused by step loop

  // ---- 6 ODE unfolds, v resident in LDS ----
  float vo0 = 0.f, vo1 = 0.f;
  for (int step = 0; step < UNFOLDS; ++step) {
    Acc8 acc = pass_accum<PACKED>(pH, pW, sigmaP, muP, wP, erevP,
                                  &v_lds[0][0], &v_lds[1][0], c, j);
    red[tid] = make_float4(acc.na0.x + acc.na0.y + acc.nb0.x + acc.nb0.y,
                           acc.da0.x + acc.da0.y + acc.db0.x + acc.db0.y,
                           acc.na1.x + acc.na1.y + acc.nb1.x + acc.nb1.y,
                           acc.da1.x + acc.da1.y + acc.db1.x + acc.db1.y);
    __syncthreads();
    if (c == 0) {
      float4 a = red[j], b = red[256 + j], cc = red[512 + j], d = red[768 + j];
      float num0 = a.x + b.x + cc.x + d.x + snum0;
      float den0 = a.y + b.y + cc.y + d.y + sden0;
      float num1 = a.z + b.z + cc.z + d.z + snum1;
      float den1 = a.w + b.w + cc.w + d.w + sden1;
      float v0 = v_lds[0][j], v1 = v_lds[1][j];
      vo0 = (cmt0 * v0 + glvl + num0) / (cmt0 + glj + den0 + EPS);
      vo1 = (cmt1 * v1 + glvl + num1) / (cmt1 + glj + den1 + EPS);
      v_lds[0][j] = vo0;
      v_lds[1][j] = vo1;
    }
    __syncthreads();
  }

  if (c == 0) {
    out[b0 * Nn + j] = vo0;
    out[(b0 + 1) * Nn + j] = vo1;
  }
}

extern "C" void kernel_launch(void* const* d_in, const int* in_sizes, int n_in,
                              void* d_out, int out_size, void* d_ws, size_t ws_size,
                              hipStream_t stream) {
  const float* input   = (const float*)d_in[0];
  const float* hx      = (const float*)d_in[1];
  const float* ts      = (const float*)d_in[2];
  const float* gleak   = (const float*)d_in[3];
  const float* vleak   = (const float*)d_in[4];
  const float* cm      = (const float*)d_in[5];
  const float* sigma   = (const float*)d_in[6];
  const float* mu      = (const float*)d_in[7];
  const float* w       = (const float*)d_in[8];
  const float* erev    = (const float*)d_in[9];
  const float* ssigma  = (const float*)d_in[10];
  const float* smu     = (const float*)d_in[11];
  const float* sw      = (const float*)d_in[12];
  const float* serev   = (const float*)d_in[13];
  const float* input_w = (const float*)d_in[14];
  const float* input_b = (const float*)d_in[15];
  float* out = (float*)d_out;

  // pH 256KB | sH 256KB | pW 128KB | sW 128KB = 768KB
  const size_t need = (size_t)PLANE * (sizeof(HQ) * 2 + sizeof(WQ) * 2);
  if (ws_size >= need) {
    HQ* pH = (HQ*)d_ws;
    HQ* sH = pH + PLANE;
    WQ* pW = (WQ*)(sH + PLANE);
    WQ* sW = pW + PLANE;
    pack_kernel<<<PLANE / 256, 256, 0, stream>>>(sigma, mu, w, erev, ssigma,
                                                 smu, sw, serev, pH, pW, sH, sW);
    ltc_kernel<true><<<Bb / 2, 1024, 0, stream>>>(
        input, hx, ts, gleak, vleak, cm, input_w, input_b, pH, pW, sH, sW,
        sigma, mu, w, erev, ssigma, smu, sw, serev, out);
  } else {
    ltc_kernel<false><<<Bb / 2, 1024, 0, stream>>>(
        input, hx, ts, gleak, vleak, cm, input_w, input_b,
        nullptr, nullptr, nullptr, nullptr,
        sigma, mu, w, erev, ssigma, smu, sw, serev, out);
  }
}